// Round 3
// baseline (960.629 us; speedup 1.0000x reference)
//
#include <hip/hip_runtime.h>
#include <math.h>

#define S1f 0.17677669529663687f  // 1/sqrt(32)

// CG table in device global: 15 paths x 128 floats (i*25+j*5+k packing).
__device__ float g_cg[1920];

// ---------------- on-device CG table construction (mirrors reference) ----------------
struct cplx { double re, im; };
__device__ inline cplx cmul(cplx a, cplx b){ return {a.re*b.re - a.im*b.im, a.re*b.im + a.im*b.re}; }

__device__ inline double factd(int n){ double f=1.0; for(int i=2;i<=n;++i) f*=(double)i; return f; }

__device__ double su2cg(int j1,int j2,int j3,int m1,int m2){
  int m3 = m1+m2;
  if (m3 < -j3 || m3 > j3) return 0.0;
  double pref = sqrt((2.0*j3+1.0)*factd(j3+j1-j2)*factd(j3-j1+j2)*factd(j1+j2-j3)/factd(j1+j2+j3+1));
  pref *= sqrt(factd(j3+m3)*factd(j3-m3)*factd(j1-m1)*factd(j1+m1)*factd(j2-m2)*factd(j2+m2));
  double s = 0.0;
  for (int k=0;k<=j1+j2-j3;++k){
    int d1=j1+j2-j3-k, d2=j1-m1-k, d3=j2+m2-k, d4=j3-j2+m1+k, d5=j3-j1-m2+k;
    if (d1<0||d2<0||d3<0||d4<0||d5<0) continue;
    s += ((k&1)?-1.0:1.0)/(factd(k)*factd(d1)*factd(d2)*factd(d3)*factd(d4)*factd(d5));
  }
  return pref*s;
}

__device__ void qmat(int l, cplx q[5][5]){
  for (int r=0;r<5;++r) for (int c=0;c<5;++c){ q[r][c].re=0.0; q[r][c].im=0.0; }
  const double rs2 = 0.70710678118654752440;
  for (int m=-l;m<0;++m){
    q[l+m][l-m].re = rs2;           // q[l+m, l+|m|] = 1/sqrt2
    q[l+m][l+m].im = -rs2;          // q[l+m, l-|m|] = -i/sqrt2
  }
  q[l][l].re = 1.0;
  for (int m=1;m<=l;++m){
    double sg = (m&1)?-1.0:1.0;
    q[l+m][l+m].re = sg*rs2;
    q[l+m][l-m].im = sg*rs2;
  }
  cplx ph;
  if (l==0){ ph.re=1.0; ph.im=0.0; }
  else if (l==1){ ph.re=0.0; ph.im=-1.0; }  // (-i)^1
  else { ph.re=-1.0; ph.im=0.0; }           // (-i)^2
  for (int r=0;r<5;++r) for (int c=0;c<5;++c) q[r][c] = cmul(ph, q[r][c]);
}

__device__ const int PL[15][3] = {
 {0,0,0},{0,1,1},{0,2,2},{1,0,1},{1,1,0},{1,1,1},{1,1,2},{1,2,1},{1,2,2},
 {2,0,2},{2,1,1},{2,1,2},{2,2,0},{2,2,1},{2,2,2}};

__global__ __launch_bounds__(64) void init_cg(){
  int p = blockIdx.x, tid = threadIdx.x;
  int l1=PL[p][0], l2=PL[p][1], l3=PL[p][2];
  int n1=2*l1+1, n2=2*l2+1, n3=2*l3+1, tot=n1*n2*n3;
  __shared__ double C[125], Tre[125], Tim[125];
  for (int idx=tid; idx<tot; idx+=64){
    int i=idx/(n2*n3), r=idx-i*(n2*n3), k=r/n3, m=r-k*n3;
    int m1=i-l1, m2=k-l2, m3=m-l3;
    C[idx] = (m3==m1+m2) ? su2cg(l1,l2,l3,m1,m2) : 0.0;
  }
  __syncthreads();
  cplx q1[5][5], q2[5][5], q3[5][5];
  qmat(l1,q1); qmat(l2,q2); qmat(l3,q3);
  double pr=0.0, pim=0.0;
  for (int idx=tid; idx<tot; idx+=64){
    int j=idx/(n2*n3), r=idx-j*(n2*n3), L=r/n3, n=r-L*n3;
    double are=0.0, aim=0.0;
    for (int i=0;i<n1;++i) for (int k=0;k<n2;++k){
      int m = (i-l1)+(k-l2)+l3;                 // m3 index
      if (m<0 || m>=n3) continue;
      double cv = C[(i*n2+k)*n3+m];
      if (cv==0.0) continue;
      cplx tq = cmul(q1[i][j], q2[k][L]);
      cplx qc; qc.re = q3[m][n].re; qc.im = -q3[m][n].im;
      tq = cmul(tq, qc);
      are += tq.re*cv; aim += tq.im*cv;
    }
    Tre[idx]=are; Tim[idx]=aim;
    pr += are*are; pim += aim*aim;
  }
  for (int off=1; off<64; off<<=1){ pr += __shfl_xor(pr,off); pim += __shfl_xor(pim,off); }
  int useIm = (sqrt(pr) < 1e-6) ? 1 : 0;
  double norm = sqrt(useIm ? pim : pr);
  // fold per-path TP coefficient: sqrt((2l3+1)/(MUL*MUL*N_TO[l3])), N_TO={3,6,6}
  double co;
  if (l3==0) co = sqrt(1.0/3072.0);
  else if (l3==1) co = sqrt(3.0/6144.0);
  else co = sqrt(5.0/6144.0);
  double scale = co/norm;
  __syncthreads();
  for (int idx=tid; idx<128; idx+=64){
    float v=0.f;
    if (idx<125){
      int a=idx/25, r=idx-a*25, b=r/5, c=r-b*5;
      if (a<n1 && b<n2 && c<n3){
        int src=(a*n2+b)*n3+c;
        double tv = useIm ? Tim[src] : Tre[src];
        v = (float)(tv*scale);
      }
    }
    g_cg[p*128+idx]=v;
  }
}

// ---------------- main fused kernel ----------------
// block: 256 threads = 16 tokens (t) x 16 slots (sl); 512 blocks x 16 tokens = 8192
// LDS: y_s 18496B + buf 10368B + Gb 12800B = 41664B  (Gb chunked by UC=8: 8*25*16 max)
__device__ const int OFFL[3] = {0,32,128};

template<int L1,int L2,int L3>
__device__ __forceinline__ void do_path(int p,
    const float* __restrict__ Wtp,
    const float* y_s, float* buf, float* Gb,
    int tid, int t, int sl, float (&acc)[4][5])
{
  constexpr int n1=2*L1+1, n2=2*L2+1, K=2*L3+1, njk=n2*K;
  constexpr int o1 = (L1==0)?0:((L1==1)?32:128);
  constexpr int o2 = (L2==0)?0:((L2==1)?32:128);
  constexpr int UC = 8;  // u-channels per G chunk; Gb holds UC*njk*16 <= 3200 floats
  const float* cgp = g_cg + p*128;
  const int q4 = (sl&7)*4, v0 = (sl>>3)*16;

  for (int u0=0; u0<32; u0+=UC){
    // G-step: Gb[uu][e=(j*K+k)][t] = sum_i y1[t,u0+uu,i]*CG[i,j,k] (coeff folded in CG)
    const int tot = UC*njk*16;
    for (int idx=tid; idx<tot; idx+=256){
      int uu = idx/(njk*16); int r = idx - uu*(njk*16); int e = r>>4; int tt = r&15;
      int j = e/K, k = e - j*K;
      float g = 0.f;
      #pragma unroll
      for (int i=0;i<n1;++i) g += y_s[tt*289 + o1 + (u0+uu)*n1 + i]*cgp[i*25 + j*5 + k];
      Gb[idx] = g;
    }
    __syncthreads();

    for (int uu=0; uu<UC; ++uu){
      int u = u0+uu;
      // tmp-step: tmp[k][v][t] = sum_j G[u][j,k][t]*y2[t,v,j]
      const float* gu = Gb + uu*(njk*16) + t;
      #pragma unroll
      for (int m=0;m<2;++m){
        int v = sl*2+m;
        float tv[K];
        #pragma unroll
        for (int k=0;k<K;++k) tv[k]=0.f;
        #pragma unroll
        for (int j=0;j<n2;++j){
          float yv = y_s[t*289 + o2 + v*n2 + j];
          #pragma unroll
          for (int k=0;k<K;++k) tv[k] += gu[(j*K+k)*16]*yv;
        }
        #pragma unroll
        for (int k=0;k<K;++k) buf[k*512 + v*16 + t] = tv[k];
      }
      __syncthreads();
      // phase B: acc[w4][k] += Wtp[p][u][v][q4+w4] * tmp[k][v][t], v over this half
      const float* wp = Wtp + (p*32+u)*1024 + q4;
      #pragma unroll 4
      for (int v=v0; v<v0+16; ++v){
        float4 wq = *(const float4*)(wp + v*32);
        #pragma unroll
        for (int k=0;k<K;++k){
          float tb = buf[k*512 + v*16 + t];
          acc[0][k] += wq.x*tb; acc[1][k] += wq.y*tb;
          acc[2][k] += wq.z*tb; acc[3][k] += wq.w*tb;
        }
      }
      __syncthreads();
    }
  }
}

template<int L3>
__device__ __forceinline__ void finish_group(const float* __restrict__ W2,
    float* buf, int t, int sl, float (&acc)[4][5], float* __restrict__ out, int tok0)
{
  constexpr int K=2*L3+1;
  constexpr int o3 = (L3==0)?0:((L3==1)?32:128);
  int q4=(sl&7)*4, h=sl>>3;
  if (h==0){
    #pragma unroll
    for (int w4=0;w4<4;++w4)
      #pragma unroll
      for (int k=0;k<K;++k) buf[(q4+w4)*(K*16) + k*16 + t] = acc[w4][k];
  }
  __syncthreads();
  if (h==1){
    #pragma unroll
    for (int w4=0;w4<4;++w4)
      #pragma unroll
      for (int k=0;k<K;++k) buf[(q4+w4)*(K*16) + k*16 + t] += acc[w4][k];
  }
  __syncthreads();
  // lin2: z[w'] = S1 * sum_w out_pre[w,k,t] * W2[L3][w][w'],  w' = sl*2 + {0,1}
  float z0[K], z1[K];
  #pragma unroll
  for (int k=0;k<K;++k){ z0[k]=0.f; z1[k]=0.f; }
  const float* w2p = W2 + L3*1024 + sl*2;
  #pragma unroll 4
  for (int u2=0;u2<32;++u2){
    float2 wv = *(const float2*)(w2p + u2*32);
    #pragma unroll
    for (int k=0;k<K;++k){
      float tb = buf[u2*(K*16) + k*16 + t];
      z0[k] += tb*wv.x; z1[k] += tb*wv.y;
    }
  }
  float* op = out + (tok0+t)*288 + o3;
  #pragma unroll
  for (int k=0;k<K;++k){ op[(sl*2)*K+k] = z0[k]*S1f; op[(sl*2+1)*K+k] = z1[k]*S1f; }
  __syncthreads();
}

__global__ __launch_bounds__(256) void sheq_main(const float* __restrict__ x,
    const float* __restrict__ W1, const float* __restrict__ Wtp,
    const float* __restrict__ W2, float* __restrict__ out)
{
  __shared__ float y_s[16*289];   // per-token post-lin1 irreps, padded stride 289
  __shared__ float buf[2592];     // x-stage / tmp[k][v][t] / out_pre[w][k][t]
  __shared__ float Gb[3200];      // G[uu<8][njk<=25][16]

  int tid = threadIdx.x;
  int t = tid&15, sl = tid>>4;
  int tok0 = blockIdx.x*16;
  const float* xb = x + tok0*288;

  // ---- lin1: y[t, off_l + w*(2l+1) + i] = S1 * sum_u x[t,u,i] * W1[l][u][w] ----
  #pragma unroll
  for (int l=0;l<3;++l){
    const int nl=2*l+1, offl=OFFL[l], rl=32*nl;
    __syncthreads();
    for (int e=tid; e<16*rl; e+=256){
      int tt=e/rl, qq=e-tt*rl;
      buf[tt*161+qq]=xb[tt*288+offl+qq];
    }
    __syncthreads();
    float a0[5], a1[5];
    for (int i=0;i<nl;++i){ a0[i]=0.f; a1[i]=0.f; }
    const float* w1p = W1 + l*1024 + sl*2;
    const float* xr = buf + t*161;
    #pragma unroll 4
    for (int u=0;u<32;++u){
      float2 wv = *(const float2*)(w1p+u*32);
      for (int i=0;i<nl;++i){ float xv=xr[u*nl+i]; a0[i]+=xv*wv.x; a1[i]+=xv*wv.y; }
    }
    float* yp = y_s + t*289 + offl;
    for (int i=0;i<nl;++i){ yp[(sl*2)*nl+i]=a0[i]*S1f; yp[(sl*2+1)*nl+i]=a1[i]*S1f; }
  }
  __syncthreads();

  // ---- TP + lin2, grouped by output l3 ----
  { // l3 = 0: paths (0,0,0)=p0, (1,1,0)=p4, (2,2,0)=p12
    float acc[4][5] = {};
    do_path<0,0,0>(0,  Wtp, y_s, buf, Gb, tid, t, sl, acc);
    do_path<1,1,0>(4,  Wtp, y_s, buf, Gb, tid, t, sl, acc);
    do_path<2,2,0>(12, Wtp, y_s, buf, Gb, tid, t, sl, acc);
    finish_group<0>(W2, buf, t, sl, acc, out, tok0);
  }
  { // l3 = 1: p1 (0,1), p3 (1,0), p5 (1,1), p7 (1,2), p10 (2,1), p13 (2,2)
    float acc[4][5] = {};
    do_path<0,1,1>(1,  Wtp, y_s, buf, Gb, tid, t, sl, acc);
    do_path<1,0,1>(3,  Wtp, y_s, buf, Gb, tid, t, sl, acc);
    do_path<1,1,1>(5,  Wtp, y_s, buf, Gb, tid, t, sl, acc);
    do_path<1,2,1>(7,  Wtp, y_s, buf, Gb, tid, t, sl, acc);
    do_path<2,1,1>(10, Wtp, y_s, buf, Gb, tid, t, sl, acc);
    do_path<2,2,1>(13, Wtp, y_s, buf, Gb, tid, t, sl, acc);
    finish_group<1>(W2, buf, t, sl, acc, out, tok0);
  }
  { // l3 = 2: p2 (0,2), p6 (1,1), p8 (1,2), p9 (2,0), p11 (2,1), p14 (2,2)
    float acc[4][5] = {};
    do_path<0,2,2>(2,  Wtp, y_s, buf, Gb, tid, t, sl, acc);
    do_path<1,1,2>(6,  Wtp, y_s, buf, Gb, tid, t, sl, acc);
    do_path<1,2,2>(8,  Wtp, y_s, buf, Gb, tid, t, sl, acc);
    do_path<2,0,2>(9,  Wtp, y_s, buf, Gb, tid, t, sl, acc);
    do_path<2,1,2>(11, Wtp, y_s, buf, Gb, tid, t, sl, acc);
    do_path<2,2,2>(14, Wtp, y_s, buf, Gb, tid, t, sl, acc);
    finish_group<2>(W2, buf, t, sl, acc, out, tok0);
  }
}

extern "C" void kernel_launch(void* const* d_in, const int* in_sizes, int n_in,
                              void* d_out, int out_size, void* d_ws, size_t ws_size,
                              hipStream_t stream) {
  const float* x   = (const float*)d_in[0];
  const float* W1  = (const float*)d_in[1];
  const float* Wtp = (const float*)d_in[2];
  const float* W2  = (const float*)d_in[3];
  float* out = (float*)d_out;

  init_cg<<<dim3(15), dim3(64), 0, stream>>>();
  sheq_main<<<dim3(512), dim3(256), 0, stream>>>(x, W1, Wtp, W2, out);
}

// Round 5
// 276.641 us; speedup vs baseline: 3.4725x; 3.4725x over previous
//
#include <hip/hip_runtime.h>
#include <hip/hip_bf16.h>
#include <math.h>

#define S1f 0.17677669529663687f  // 1/sqrt(32)

typedef float  f32x4 __attribute__((ext_vector_type(4)));
typedef short  s16x8 __attribute__((ext_vector_type(8)));

// ---------------- CG math (mirrors reference; runs per-block in phase 0) ----------------
struct cplx { double re, im; };
__device__ __forceinline__ cplx cmul(cplx a, cplx b){ return {a.re*b.re - a.im*b.im, a.re*b.im + a.im*b.re}; }
__device__ __forceinline__ double factd(int n){ double f=1.0; for(int i=2;i<=n;++i) f*=(double)i; return f; }

__device__ double su2cg(int j1,int j2,int j3,int m1,int m2){
  int m3 = m1+m2;
  if (m3 < -j3 || m3 > j3) return 0.0;
  double pref = sqrt((2.0*j3+1.0)*factd(j3+j1-j2)*factd(j3-j1+j2)*factd(j1+j2-j3)/factd(j1+j2+j3+1));
  pref *= sqrt(factd(j3+m3)*factd(j3-m3)*factd(j1-m1)*factd(j1+m1)*factd(j2-m2)*factd(j2+m2));
  double s = 0.0;
  for (int k=0;k<=j1+j2-j3;++k){
    int d1=j1+j2-j3-k, d2=j1-m1-k, d3=j2+m2-k, d4=j3-j2+m1+k, d5=j3-j1-m2+k;
    if (d1<0||d2<0||d3<0||d4<0||d5<0) continue;
    s += ((k&1)?-1.0:1.0)/(factd(k)*factd(d1)*factd(d2)*factd(d3)*factd(d4)*factd(d5));
  }
  return pref*s;
}

// real->complex SH change of basis, single entry q[r][c] for given l (incl (-i)^l phase)
__device__ __forceinline__ cplx q_entry(int l, int r, int c){
  const double rs2 = 0.70710678118654752440;
  double re=0.0, im=0.0;
  if (r < l){                    // m = r-l < 0
    if (c == 2*l-r) re = rs2;    // col l+|m|
    if (c == r)     im = -rs2;   // col l-|m|
  } else if (r == l){
    if (c == l) re = 1.0;
  } else {                       // m = r-l > 0
    double sg = ((r-l)&1)?-1.0:1.0;
    if (c == r)     re = sg*rs2;
    if (c == 2*l-r) im = sg*rs2;
  }
  cplx ph;
  if (l==0)      ph = {1.0, 0.0};
  else if (l==1) ph = {0.0,-1.0};   // (-i)^1
  else           ph = {-1.0,0.0};   // (-i)^2
  return cmul(ph, (cplx){re, im});
}

__device__ const int PL[15][3] = {
 {0,0,0},{0,1,1},{0,2,2},{1,0,1},{1,1,0},{1,1,1},{1,1,2},{1,2,1},{1,2,2},
 {2,0,2},{2,1,1},{2,1,2},{2,2,0},{2,2,1},{2,2,2}};

__device__ const int OFFL[3] = {0,32,128};

// ---------------- TP path: A-frag built in registers, B-frag from Wtp inline ----------------
// MFMA 16x16x32 bf16: A row=token(lane&15), A k=v=(lane>>4)*8+j; B col=w(lane&15), B k=v.
// C/D: col=lane&15 (w), row=(lane>>4)*4+reg (token).
template<int L1,int L2,int L3,int P>
__device__ __forceinline__ void tp_path(const float* __restrict__ y_s,
    const float* __restrict__ cg_lds, const float* __restrict__ Wtp,
    int lane, int wave, f32x4 (&acc)[9][2])
{
  constexpr int n1=2*L1+1, n2=2*L2+1, K=2*L3+1;
  constexpr int o1=(L1==0)?0:((L1==1)?32:128);
  constexpr int o2=(L2==0)?0:((L2==1)?32:128);
  constexpr int S0=(L3==0)?0:((L3==1)?1:4);
  const int t = lane&15, vg = lane>>4;
  const float* yt = y_s + t*289;
  float y2r[8][n2];
  #pragma unroll
  for (int vi=0;vi<8;++vi)
    #pragma unroll
    for (int j=0;j<n2;++j) y2r[vi][j] = yt[o2 + (vg*8+vi)*n2 + j];
  const float* cgp = cg_lds + P*128;

  #pragma unroll 1
  for (int uc=0;uc<4;++uc){
    const int u0 = wave*8 + uc*2;
    float y1r[2][n1];
    #pragma unroll
    for (int uu=0;uu<2;++uu)
      #pragma unroll
      for (int i=0;i<n1;++i) y1r[uu][i] = yt[o1 + (u0+uu)*n1 + i];
    // B-frags: bf16 of Wtp[p][u0+uu][v=vg*8+j][wt*16+t]  (stride-32 dword loads, L2-resident)
    s16x8 bfr[2][2];
    #pragma unroll
    for (int uu=0;uu<2;++uu)
      #pragma unroll
      for (int wt=0;wt<2;++wt){
        const float* wp = Wtp + (((P*32+u0+uu)*32 + vg*8)*32) + wt*16 + t;
        s16x8 b;
        #pragma unroll
        for (int j=0;j<8;++j){
          union { __hip_bfloat16 h; short s; } cv;
          cv.h = __float2bfloat16(wp[j*32]);
          b[j] = cv.s;
        }
        bfr[uu][wt] = b;
      }
    #pragma unroll
    for (int k=0;k<K;++k){
      float G[2][n2];
      #pragma unroll
      for (int uu=0;uu<2;++uu)
        #pragma unroll
        for (int j=0;j<n2;++j) G[uu][j]=0.f;
      #pragma unroll
      for (int i=0;i<n1;++i)
        #pragma unroll
        for (int j=0;j<n2;++j){
          float c = cgp[i*25 + j*5 + k];
          G[0][j] += y1r[0][i]*c;
          G[1][j] += y1r[1][i]*c;
        }
      #pragma unroll
      for (int uu=0;uu<2;++uu){
        s16x8 a;
        #pragma unroll
        for (int vi=0;vi<8;++vi){
          float af = 0.f;
          #pragma unroll
          for (int j=0;j<n2;++j) af += G[uu][j]*y2r[vi][j];
          union { __hip_bfloat16 h; short s; } cv;
          cv.h = __float2bfloat16(af);
          a[vi] = cv.s;
        }
        acc[S0+k][0] = __builtin_amdgcn_mfma_f32_16x16x32_bf16(a, bfr[uu][0], acc[S0+k][0],0,0,0);
        acc[S0+k][1] = __builtin_amdgcn_mfma_f32_16x16x32_bf16(a, bfr[uu][1], acc[S0+k][1],0,0,0);
      }
    }
  }
}

template<int L3>
__device__ __forceinline__ void lin2_group(const float* __restrict__ smem,
    const float* __restrict__ W2, int t, int sl, float* __restrict__ op)
{
  constexpr int K=2*L3+1;
  constexpr int o3=(L3==0)?0:((L3==1)?32:128);
  constexpr int B=(L3==0)?0:((L3==1)?1:4);
  float z0[K], z1[K];
  #pragma unroll
  for (int k=0;k<K;++k){ z0[k]=0.f; z1[k]=0.f; }
  const float* w2p = W2 + L3*1024 + sl*2;
  #pragma unroll 4
  for (int w=0;w<32;++w){
    float2 wv = *(const float2*)(w2p + w*32);
    #pragma unroll
    for (int k=0;k<K;++k){
      float tb = smem[(B+k)*528 + t*33 + w];
      z0[k] += tb*wv.x; z1[k] += tb*wv.y;
    }
  }
  #pragma unroll
  for (int k=0;k<K;++k){
    op[o3 + (sl*2)*K + k]   = z0[k]*S1f;
    op[o3 + (sl*2+1)*K + k] = z1[k]*S1f;
  }
}

// ---------------- single self-contained kernel ----------------
// 512 blocks x 256 thr; block = 16 tokens; 4 waves; wave owns u in [wave*8, wave*8+8).
// No device globals, no cross-kernel state: CG built per block in LDS (phase 0).
__global__ __launch_bounds__(256,2) void sheq_main(const float* __restrict__ x,
    const float* __restrict__ W1, const float* __restrict__ Wtp,
    const float* __restrict__ W2, float* __restrict__ out)
{
  __shared__ float y_s[16*289];                 // post-lin1 irreps
  __shared__ __align__(16) float smem[4752];    // phase0 dbl scratch / lin1 staging / reduction
  __shared__ float cg_lds[1920];                // CG, coeff folded: [p][i*25+j*5+k]

  int tid = threadIdx.x;
  int t = tid&15, sl = tid>>4;
  int lane = tid&63, wave = tid>>6;
  int tok0 = blockIdx.x*16;
  const float* xb = x + tok0*288;

  // ---- phase 0: build CG in LDS; wave handles paths {wave, wave+4, wave+8, wave+12} ----
  {
    double* dw  = ((double*)smem) + wave*384;
    double* Cp  = dw;
    double* TreP= dw + 128;
    double* TimP= dw + 256;
    #pragma unroll 1
    for (int c=0;c<4;++c){
      int p = c*4 + wave;
      bool act = (p < 15);
      int l1=0,l2=0,l3=0;
      if (act){ l1=PL[p][0]; l2=PL[p][1]; l3=PL[p][2]; }
      int n1=2*l1+1, n2=2*l2+1, n3=2*l3+1, tot=n1*n2*n3;
      if (act){
        for (int idx=lane; idx<tot; idx+=64){
          int i=idx/(n2*n3), r=idx-i*(n2*n3), k=r/n3, m=r-k*n3;
          Cp[idx] = ((i-l1)+(k-l2)==(m-l3)) ? su2cg(l1,l2,l3,i-l1,k-l2) : 0.0;
        }
      }
      __syncthreads();
      double pr=0.0, pim=0.0;
      if (act){
        for (int idx=lane; idx<tot; idx+=64){
          int j=idx/(n2*n3), r=idx-j*(n2*n3), L=r/n3, n=r-L*n3;
          double are=0.0, aim=0.0;
          for (int i=0;i<n1;++i) for (int k=0;k<n2;++k){
            int m=(i-l1)+(k-l2)+l3;
            if (m<0 || m>=n3) continue;
            double cv = Cp[(i*n2+k)*n3+m];
            if (cv==0.0) continue;
            cplx t1=q_entry(l1,i,j), t2=q_entry(l2,k,L), t3=q_entry(l3,m,n);
            t3.im = -t3.im;
            cplx tq = cmul(cmul(t1,t2),t3);
            are += tq.re*cv; aim += tq.im*cv;
          }
          TreP[idx]=are; TimP[idx]=aim;
          pr += are*are; pim += aim*aim;
        }
      }
      for (int off=1; off<64; off<<=1){ pr += __shfl_xor(pr,off); pim += __shfl_xor(pim,off); }
      __syncthreads();
      if (act){
        int useIm = (sqrt(pr) < 1e-6) ? 1 : 0;
        double norm = sqrt(useIm ? pim : pr);
        double co = (l3==0)? sqrt(1.0/3072.0) : ((l3==1)? sqrt(3.0/6144.0) : sqrt(5.0/6144.0));
        double scale = co/norm;
        for (int idx=lane; idx<128; idx+=64){
          float v=0.f;
          if (idx<125){
            int a=idx/25, r=idx-a*25, b=r/5, cc=r-b*5;
            if (a<n1 && b<n2 && cc<n3){
              int src=(a*n2+b)*n3+cc;
              double tv = useIm ? TimP[src] : TreP[src];
              v = (float)(tv*scale);
            }
          }
          cg_lds[p*128+idx]=v;
        }
      }
      __syncthreads();
    }
  }

  // ---- phase 1: lin1 (fp32 VALU) ----
  #pragma unroll
  for (int l=0;l<3;++l){
    const int nl=2*l+1, offl=OFFL[l], rl=32*nl;
    __syncthreads();
    for (int e=tid; e<16*rl; e+=256){
      int tt=e/rl, qq=e-tt*rl;
      smem[tt*161+qq]=xb[tt*288+offl+qq];
    }
    __syncthreads();
    float a0[5], a1[5];
    for (int i=0;i<nl;++i){ a0[i]=0.f; a1[i]=0.f; }
    const float* w1p = W1 + l*1024 + sl*2;
    const float* xr = smem + t*161;
    #pragma unroll 4
    for (int u=0;u<32;++u){
      float2 wv = *(const float2*)(w1p+u*32);
      for (int i=0;i<nl;++i){ float xv=xr[u*nl+i]; a0[i]+=xv*wv.x; a1[i]+=xv*wv.y; }
    }
    float* yp = y_s + t*289 + offl;
    for (int i=0;i<nl;++i){ yp[(sl*2)*nl+i]=a0[i]*S1f; yp[(sl*2+1)*nl+i]=a1[i]*S1f; }
  }
  __syncthreads();

  // ---- phase 2: TP via MFMA, barrier-free ----
  f32x4 acc[9][2];
  #pragma unroll
  for (int s=0;s<9;++s){ acc[s][0]=(f32x4){0.f,0.f,0.f,0.f}; acc[s][1]=(f32x4){0.f,0.f,0.f,0.f}; }

  tp_path<0,0,0, 0>(y_s,cg_lds,Wtp,lane,wave,acc);
  tp_path<0,1,1, 1>(y_s,cg_lds,Wtp,lane,wave,acc);
  tp_path<0,2,2, 2>(y_s,cg_lds,Wtp,lane,wave,acc);
  tp_path<1,0,1, 3>(y_s,cg_lds,Wtp,lane,wave,acc);
  tp_path<1,1,0, 4>(y_s,cg_lds,Wtp,lane,wave,acc);
  tp_path<1,1,1, 5>(y_s,cg_lds,Wtp,lane,wave,acc);
  tp_path<1,1,2, 6>(y_s,cg_lds,Wtp,lane,wave,acc);
  tp_path<1,2,1, 7>(y_s,cg_lds,Wtp,lane,wave,acc);
  tp_path<1,2,2, 8>(y_s,cg_lds,Wtp,lane,wave,acc);
  tp_path<2,0,2, 9>(y_s,cg_lds,Wtp,lane,wave,acc);
  tp_path<2,1,1,10>(y_s,cg_lds,Wtp,lane,wave,acc);
  tp_path<2,1,2,11>(y_s,cg_lds,Wtp,lane,wave,acc);
  tp_path<2,2,0,12>(y_s,cg_lds,Wtp,lane,wave,acc);
  tp_path<2,2,1,13>(y_s,cg_lds,Wtp,lane,wave,acc);
  tp_path<2,2,2,14>(y_s,cg_lds,Wtp,lane,wave,acc);

  // ---- phase 3: cross-wave reduction into smem[s][t][w] (stride 33) ----
  for (int wv=0;wv<4;++wv){
    if (wave==wv){
      #pragma unroll
      for (int s=0;s<9;++s)
        #pragma unroll
        for (int wt=0;wt<2;++wt)
          #pragma unroll
          for (int r=0;r<4;++r){
            int row = (lane>>4)*4 + r, col = wt*16 + (lane&15);
            float* pp = &smem[s*528 + row*33 + col];
            if (wv==0) *pp = acc[s][wt][r]; else *pp += acc[s][wt][r];
          }
    }
    __syncthreads();
  }

  // ---- lin2 (fp32 VALU) ----
  float* op = out + (tok0+t)*288;
  lin2_group<0>(smem, W2, t, sl, op);
  lin2_group<1>(smem, W2, t, sl, op);
  lin2_group<2>(smem, W2, t, sl, op);
}

extern "C" void kernel_launch(void* const* d_in, const int* in_sizes, int n_in,
                              void* d_out, int out_size, void* d_ws, size_t ws_size,
                              hipStream_t stream) {
  const float* x   = (const float*)d_in[0];
  const float* W1  = (const float*)d_in[1];
  const float* Wtp = (const float*)d_in[2];
  const float* W2  = (const float*)d_in[3];
  float* out = (float*)d_out;

  sheq_main<<<dim3(512), dim3(256), 0, stream>>>(x, W1, Wtp, W2, out);
}